// Round 3
// baseline (392.466 us; speedup 1.0000x reference)
//
#include <hip/hip_runtime.h>

// Problem constants
static constexpr int   Cc  = 21;
static constexpr int   HWn = 512 * 512;         // 262144 = 2^18
static constexpr int   Nn  = 8 * HWn;           // 2097152 pixels
static constexpr float MAXM = 0.5f;
static constexpr float Sc   = 30.0f;

// ws layout (bytes): 0: int counts[21] ; 96: double acc ; 104: int done
static constexpr int WS_COUNTS = 0;
static constexpr int WS_ACC    = 96;
static constexpr int WS_DONE   = 104;

// ---------------------------------------------------------------------------
// K1: class histogram. One int4 (4 labels) per thread, LDS-local atomics,
// then 21 global atomics per block.
__global__ __launch_bounds__(256) void hist_kernel(const int4* __restrict__ t4,
                                                   int* __restrict__ counts) {
    __shared__ int lh[Cc];
    int t = threadIdx.x;
    if (t < Cc) lh[t] = 0;
    __syncthreads();
    int tid = blockIdx.x * 256 + t;           // tid in [0, Nn/4)
    int4 v = t4[tid];
    atomicAdd(&lh[v.x], 1);
    atomicAdd(&lh[v.y], 1);
    atomicAdd(&lh[v.z], 1);
    atomicAdd(&lh[v.w], 1);
    __syncthreads();
    if (t < Cc) atomicAdd(&counts[t], lh[t]);
}

// ---------------------------------------------------------------------------
// K2: fused m_list + loss + finalize.
// Two-pass logsumexp with ALL 21 float4 class loads register-resident
// (keeps 21 loads in flight per wave — the round-2 online version collapsed
// to 20 VGPRs and serialized loads: 553 GB/s. Register residency is the MLP.)
__global__ __launch_bounds__(256) void loss_kernel(const float* __restrict__ pred,
                                                   const int4* __restrict__ t4,
                                                   const int* __restrict__ counts,
                                                   double* __restrict__ acc,
                                                   int* __restrict__ done,
                                                   float* __restrict__ out) {
    __shared__ float s_sm[Cc];   // m_list values (unscaled)
    __shared__ float wsum[4];

    int t = threadIdx.x;
    if (t < Cc) s_sm[t] = 1.0f / sqrtf(sqrtf((float)counts[t] + 1e-4f));
    __syncthreads();

    // every thread computes the max itself (broadcast LDS reads, no races)
    float mxm = s_sm[0];
    #pragma unroll
    for (int i = 1; i < Cc; ++i) mxm = fmaxf(mxm, s_sm[i]);
    float scl = Sc * (MAXM / mxm);            // S*m_list[c] = s_sm[c] * scl

    int tid = blockIdx.x * 256 + t;           // tid in [0, Nn/4)
    int n0  = tid * 4;
    int b   = n0 >> 18;                       // HWn = 2^18
    int hw  = n0 & (HWn - 1);
    const float4* p4 = (const float4*)(pred + (size_t)b * Cc * HWn + hw);

    int4 y4 = t4[tid];
    int ys[4] = {y4.x, y4.y, y4.z, y4.w};
    float smy[4];
    #pragma unroll
    for (int k = 0; k < 4; ++k) smy[k] = s_sm[ys[k]] * scl;

    // pass 1: load everything into registers, margin-adjust, track max
    float v[Cc][4];
    float mx[4] = {-1e30f, -1e30f, -1e30f, -1e30f};
    float vy[4] = {0.f, 0.f, 0.f, 0.f};

    #pragma unroll
    for (int c = 0; c < Cc; ++c) {
        float4 x = p4[(size_t)c * (HWn / 4)];
        float xs[4] = {x.x, x.y, x.z, x.w};
        #pragma unroll
        for (int k = 0; k < 4; ++k) {
            bool  isy = (c == ys[k]);
            float val = fmaf(Sc, xs[k], isy ? -smy[k] : 0.0f);
            v[c][k] = val;
            mx[k] = fmaxf(mx[k], val);
            vy[k] = isy ? val : vy[k];
        }
    }

    // pass 2: sum of exps from registers
    float nll = 0.0f;
    #pragma unroll
    for (int k = 0; k < 4; ++k) {
        float sum = 0.0f;
        #pragma unroll
        for (int c = 0; c < Cc; ++c) sum += __expf(v[c][k] - mx[k]);
        nll += __logf(sum) + mx[k] - vy[k];
    }

    // wave (64-lane) reduce
    #pragma unroll
    for (int o = 32; o >= 1; o >>= 1) nll += __shfl_down(nll, o);

    int wave = t >> 6;
    int lane = t & 63;
    if (lane == 0) wsum[wave] = nll;
    __syncthreads();
    if (t == 0) {
        float bsum = wsum[0] + wsum[1] + wsum[2] + wsum[3];
        atomicAdd(acc, (double)bsum);
        __threadfence();                      // release
        int prev = atomicAdd(done, 1);
        if (prev == (int)gridDim.x - 1) {     // last block finalizes
            __threadfence();                  // acquire
            double total = atomicAdd(acc, 0.0);  // device-scope atomic read
            out[0] = (float)(total / (double)Nn);
        }
    }
}

extern "C" void kernel_launch(void* const* d_in, const int* in_sizes, int n_in,
                              void* d_out, int out_size, void* d_ws, size_t ws_size,
                              hipStream_t stream) {
    const float* pred   = (const float*)d_in[0];
    const int*   target = (const int*)d_in[1];
    float*       out    = (float*)d_out;

    char* ws = (char*)d_ws;
    int*    counts = (int*)(ws + WS_COUNTS);
    double* acc    = (double*)(ws + WS_ACC);
    int*    done   = (int*)(ws + WS_DONE);

    hipMemsetAsync(d_ws, 0, 256, stream);     // zero counts + acc + done

    const int nvec   = Nn / 4;                // 524288
    const int blocks = nvec / 256;            // 2048

    hist_kernel<<<blocks, 256, 0, stream>>>((const int4*)target, counts);
    loss_kernel<<<blocks, 256, 0, stream>>>(pred, (const int4*)target, counts,
                                            acc, done, out);
}

// Round 4
// 274.457 us; speedup vs baseline: 1.4300x; 1.4300x over previous
//
#include <hip/hip_runtime.h>

// Problem constants
static constexpr int   Cc  = 21;
static constexpr int   HWn = 512 * 512;         // 262144 = 2^18
static constexpr int   Nn  = 8 * HWn;           // 2097152 pixels
static constexpr float MAXM = 0.5f;
static constexpr float Sc   = 30.0f;

// ws layout (bytes): 0: int counts[21] ; 96: double acc ; 128: float sm[21]
static constexpr int WS_COUNTS = 0;
static constexpr int WS_ACC    = 96;
static constexpr int WS_SM     = 128;

// ---------------------------------------------------------------------------
// K1: class histogram. One int4 (4 labels) per thread, LDS-local atomics,
// then 21 global atomics per block.
__global__ __launch_bounds__(256) void hist_kernel(const int4* __restrict__ t4,
                                                   int* __restrict__ counts) {
    __shared__ int lh[Cc];
    int t = threadIdx.x;
    if (t < Cc) lh[t] = 0;
    __syncthreads();
    int tid = blockIdx.x * 256 + t;           // tid in [0, Nn/4)
    int4 v = t4[tid];
    atomicAdd(&lh[v.x], 1);
    atomicAdd(&lh[v.y], 1);
    atomicAdd(&lh[v.z], 1);
    atomicAdd(&lh[v.w], 1);
    __syncthreads();
    if (t < Cc) atomicAdd(&counts[t], lh[t]);
}

// ---------------------------------------------------------------------------
// K2: m_list = (counts + 1e-4)^(-1/4); m_list *= MAX_M / max(m_list);
// store sm[c] = S * m_list[c]. Single wave of 64.
__global__ __launch_bounds__(64) void mlist_kernel(const int* __restrict__ counts,
                                                   float* __restrict__ sm) {
    int t = threadIdx.x;
    float mval = 0.0f;
    if (t < Cc) {
        float cnt = (float)counts[t] + 1e-4f;
        mval = 1.0f / sqrtf(sqrtf(cnt));      // x^-0.25
    }
    float mx = mval;
    #pragma unroll
    for (int o = 32; o >= 1; o >>= 1) mx = fmaxf(mx, __shfl_down(mx, o));
    mx = __shfl(mx, 0);
    if (t < Cc) sm[t] = Sc * mval * (MAXM / mx);
}

// ---------------------------------------------------------------------------
// K3: main loss. TWO pixels per thread (float2 loads across the 21-class
// stride). Explicit register load array x[21] (42 VGPRs of data) keeps all
// 21 loads in flight per lane without tripping the register allocator into
// spilling (round 3: v[21][4] -> VGPR=52 -> spill/remat -> 190 us).
__global__ __launch_bounds__(256) void loss_kernel(const float* __restrict__ pred,
                                                   const int2* __restrict__ t2,
                                                   const float* __restrict__ smg,
                                                   double* __restrict__ acc) {
    __shared__ float s_sm[Cc];
    __shared__ float wsum[4];
    int t = threadIdx.x;
    if (t < Cc) s_sm[t] = smg[t];
    __syncthreads();

    int tid = blockIdx.x * 256 + t;           // tid in [0, Nn/2)
    int n0  = tid * 2;
    int b   = n0 >> 18;                       // HWn = 2^18
    int hw  = n0 & (HWn - 1);
    const float2* p2 = (const float2*)(pred + (size_t)b * Cc * HWn + hw);

    // issue all 21 loads back-to-back (memory-level parallelism)
    float2 x[Cc];
    #pragma unroll
    for (int c = 0; c < Cc; ++c) x[c] = p2[(size_t)c * (HWn / 2)];

    int2 y2 = t2[tid];
    int   ys[2]  = {y2.x, y2.y};
    float smy[2] = {s_sm[ys[0]], s_sm[ys[1]]};

    float mx[2] = {-1e30f, -1e30f};
    float vy[2] = {0.f, 0.f};
    float v[Cc][2];
    #pragma unroll
    for (int c = 0; c < Cc; ++c) {
        float xs[2] = {x[c].x, x[c].y};
        #pragma unroll
        for (int k = 0; k < 2; ++k) {
            float val = Sc * xs[k] - (c == ys[k] ? smy[k] : 0.0f);
            v[c][k] = val;
            mx[k] = fmaxf(mx[k], val);
            if (c == ys[k]) vy[k] = val;
        }
    }

    float nll = 0.0f;
    #pragma unroll
    for (int k = 0; k < 2; ++k) {
        float sum = 0.0f;
        #pragma unroll
        for (int c = 0; c < Cc; ++c) sum += __expf(v[c][k] - mx[k]);
        nll += __logf(sum) + mx[k] - vy[k];
    }

    // wave (64-lane) reduce
    #pragma unroll
    for (int o = 32; o >= 1; o >>= 1) nll += __shfl_down(nll, o);

    int wave = t >> 6;
    int lane = t & 63;
    if (lane == 0) wsum[wave] = nll;
    __syncthreads();
    if (t == 0) {
        float bsum = wsum[0] + wsum[1] + wsum[2] + wsum[3];
        atomicAdd(acc, (double)bsum);
    }
}

// ---------------------------------------------------------------------------
// K4: finalize mean.
__global__ void final_kernel(const double* __restrict__ acc, float* __restrict__ out) {
    out[0] = (float)(acc[0] / (double)Nn);
}

extern "C" void kernel_launch(void* const* d_in, const int* in_sizes, int n_in,
                              void* d_out, int out_size, void* d_ws, size_t ws_size,
                              hipStream_t stream) {
    const float* pred   = (const float*)d_in[0];
    const int*   target = (const int*)d_in[1];
    float*       out    = (float*)d_out;

    char* ws = (char*)d_ws;
    int*    counts = (int*)(ws + WS_COUNTS);
    double* acc    = (double*)(ws + WS_ACC);
    float*  sm     = (float*)(ws + WS_SM);

    hipMemsetAsync(d_ws, 0, 256, stream);     // zero counts + acc

    hist_kernel <<<Nn / 4 / 256, 256, 0, stream>>>((const int4*)target, counts);
    mlist_kernel<<<1,            64,  0, stream>>>(counts, sm);
    loss_kernel <<<Nn / 2 / 256, 256, 0, stream>>>(pred, (const int2*)target, sm, acc);
    final_kernel<<<1,            1,   0, stream>>>(acc, out);
}

// Round 5
// 272.445 us; speedup vs baseline: 1.4405x; 1.0074x over previous
//
#include <hip/hip_runtime.h>

// Problem constants
static constexpr int   Cc  = 21;
static constexpr int   HWn = 512 * 512;         // 262144 = 2^18
static constexpr int   Nn  = 8 * HWn;           // 2097152 pixels
static constexpr float MAXM  = 0.5f;
static constexpr float Sc    = 30.0f;
static constexpr float LOG2E = 1.4426950408889634f;
static constexpr float LN2   = 0.6931471805599453f;

// ws layout (bytes): 0: int counts[21] ; 96: double acc ; 128: float sm2[21]
static constexpr int WS_COUNTS = 0;
static constexpr int WS_ACC    = 96;
static constexpr int WS_SM     = 128;

// ---------------------------------------------------------------------------
// K1: class histogram. One int4 (4 labels) per thread, LDS-local atomics,
// then 21 global atomics per block.
__global__ __launch_bounds__(256) void hist_kernel(const int4* __restrict__ t4,
                                                   int* __restrict__ counts) {
    __shared__ int lh[Cc];
    int t = threadIdx.x;
    if (t < Cc) lh[t] = 0;
    __syncthreads();
    int tid = blockIdx.x * 256 + t;           // tid in [0, Nn/4)
    int4 v = t4[tid];
    atomicAdd(&lh[v.x], 1);
    atomicAdd(&lh[v.y], 1);
    atomicAdd(&lh[v.z], 1);
    atomicAdd(&lh[v.w], 1);
    __syncthreads();
    if (t < Cc) atomicAdd(&counts[t], lh[t]);
}

// ---------------------------------------------------------------------------
// K2: m_list = (counts + 1e-4)^(-1/4); m_list *= MAX_M / max(m_list);
// store sm2[c] = S * m_list[c] * LOG2E (margin in base-2 logit domain).
__global__ __launch_bounds__(64) void mlist_kernel(const int* __restrict__ counts,
                                                   float* __restrict__ sm2) {
    int t = threadIdx.x;
    float mval = 0.0f;
    if (t < Cc) {
        float cnt = (float)counts[t] + 1e-4f;
        mval = 1.0f / sqrtf(sqrtf(cnt));      // x^-0.25
    }
    float mx = mval;
    #pragma unroll
    for (int o = 32; o >= 1; o >>= 1) mx = fmaxf(mx, __shfl_down(mx, o));
    mx = __shfl(mx, 0);
    if (t < Cc) sm2[t] = Sc * LOG2E * mval * (MAXM / mx);
}

// ---------------------------------------------------------------------------
// K3: main loss. FOUR pixels per thread via float4 loads across the 21-class
// stride. x[21] float4 register array = 84 data VGPRs; pass 2 RECOMPUTES the
// margin-adjusted value from x (no second 84-reg array -> no spill; round 3's
// v[21][4]+x variant spilled at VGPR=52). Softmax in base-2 domain: one
// v_exp per element, single *LN2 at the end.
__global__ __launch_bounds__(256, 2) void loss_kernel(const float* __restrict__ pred,
                                                      const int4* __restrict__ t4,
                                                      const float* __restrict__ smg,
                                                      double* __restrict__ acc) {
    __shared__ float s_sm[Cc];
    __shared__ float wsum[4];
    int t = threadIdx.x;
    if (t < Cc) s_sm[t] = smg[t];
    __syncthreads();

    int tid = blockIdx.x * 256 + t;           // tid in [0, Nn/4)
    int n0  = tid * 4;
    int b   = n0 >> 18;                       // HWn = 2^18
    int hw  = n0 & (HWn - 1);
    const float4* p4 = (const float4*)(pred + (size_t)b * Cc * HWn + hw);

    // issue all 21 coalesced float4 loads back-to-back (MLP)
    float4 x[Cc];
    #pragma unroll
    for (int c = 0; c < Cc; ++c) x[c] = p4[(size_t)c * (HWn / 4)];

    int4 y4 = t4[tid];
    int ys[4] = {y4.x, y4.y, y4.z, y4.w};
    float smy[4];
    #pragma unroll
    for (int k = 0; k < 4; ++k) smy[k] = s_sm[ys[k]];

    const float S2 = Sc * LOG2E;

    // pass 1: max + target value (base-2 logits), nothing stored
    float mx[4] = {-1e30f, -1e30f, -1e30f, -1e30f};
    float vy[4] = {0.f, 0.f, 0.f, 0.f};
    #pragma unroll
    for (int c = 0; c < Cc; ++c) {
        float xs[4] = {x[c].x, x[c].y, x[c].z, x[c].w};
        #pragma unroll
        for (int k = 0; k < 4; ++k) {
            bool  isy = (c == ys[k]);
            float val = fmaf(S2, xs[k], isy ? -smy[k] : 0.0f);
            mx[k] = fmaxf(mx[k], val);
            vy[k] = isy ? val : vy[k];
        }
    }

    // pass 2: sum of exp2 recomputed from x
    float nll2 = 0.0f;
    #pragma unroll
    for (int k = 0; k < 4; ++k) {
        float cb = -mx[k];                    // non-target: val - mx
        float cy = -smy[k] - mx[k];           // target: val - mx
        float sum = 0.0f;
        #pragma unroll
        for (int c = 0; c < Cc; ++c) {
            float xs = (k == 0) ? x[c].x : (k == 1) ? x[c].y : (k == 2) ? x[c].z : x[c].w;
            sum += exp2f(fmaf(S2, xs, (c == ys[k]) ? cy : cb));
        }
        nll2 += __log2f(sum) + mx[k] - vy[k];
    }
    float nll = nll2 * LN2;

    // wave (64-lane) reduce
    #pragma unroll
    for (int o = 32; o >= 1; o >>= 1) nll += __shfl_down(nll, o);

    int wave = t >> 6;
    int lane = t & 63;
    if (lane == 0) wsum[wave] = nll;
    __syncthreads();
    if (t == 0) {
        float bsum = wsum[0] + wsum[1] + wsum[2] + wsum[3];
        atomicAdd(acc, (double)bsum);
    }
}

// ---------------------------------------------------------------------------
// K4: finalize mean.
__global__ void final_kernel(const double* __restrict__ acc, float* __restrict__ out) {
    out[0] = (float)(acc[0] / (double)Nn);
}

extern "C" void kernel_launch(void* const* d_in, const int* in_sizes, int n_in,
                              void* d_out, int out_size, void* d_ws, size_t ws_size,
                              hipStream_t stream) {
    const float* pred   = (const float*)d_in[0];
    const int*   target = (const int*)d_in[1];
    float*       out    = (float*)d_out;

    char* ws = (char*)d_ws;
    int*    counts = (int*)(ws + WS_COUNTS);
    double* acc    = (double*)(ws + WS_ACC);
    float*  sm     = (float*)(ws + WS_SM);

    hipMemsetAsync(d_ws, 0, 256, stream);     // zero counts + acc

    hist_kernel <<<Nn / 4 / 256, 256, 0, stream>>>((const int4*)target, counts);
    mlist_kernel<<<1,            64,  0, stream>>>(counts, sm);
    loss_kernel <<<Nn / 4 / 256, 256, 0, stream>>>(pred, (const int4*)target, sm, acc);
    final_kernel<<<1,            1,   0, stream>>>(acc, out);
}